// Round 20
// baseline (260.742 us; speedup 1.0000x reference)
//
#include <hip/hip_runtime.h>

// MTTT attention, MI355X gfx950.
// B=8, N=1024, C=1024, H=16, d=64, INNER_ITR=4, INNER_LR=1.0
//
// Algebra: inner GD loop needs only G=k^Tk/N, P=k^Tv/N, mk, mv:
//   W <- W + P - G*W - mk (x) b ;  b <- mv - mk*W   (old W,b on RHS)
// Fusion (r9): out = q·Wc_b + bc_b with Wc_{b,h} = W_{b,h} @ wp_h,
//   bc_b = b_proj + sum_c b_b[c]*wp[c,:]
// r17: g_qkv 128x256 (measured-best tile), g_out 128x128/3perCU.
// r19: stats dbuf + gd_wc fusion. r20: g_qkv ring-3 (72KB, 2 blk/CU,
//   16 waves/CU) -> ring-2 (48KB, 3 blk/CU, 24 waves/CU) — occupancy is
//   the only knob that has ever moved this kernel (14%->77us, 33%->67us).

#define SEQ    1024
#define NBATCH 8
#define DIMC   1024
#define NHEAD  16
#define HDIM   64
#define MROWS  8192      // NBATCH*SEQ
#define NQKV   3072

typedef __attribute__((ext_vector_type(8))) __bf16 bf16x8;
typedef __attribute__((ext_vector_type(4))) float  f32x4;

__device__ __forceinline__ unsigned short f2b(float f) {
  union { float f; unsigned int u; } v; v.f = f;
  unsigned int r = (v.u + 0x7FFFu + ((v.u >> 16) & 1u)) >> 16; // RNE
  return (unsigned short)r;
}

// async global->LDS, 16B per lane; LDS dest = wave-uniform base + lane*16
__device__ __forceinline__ void load_lds16(const void* g, void* l) {
  __builtin_amdgcn_global_load_lds(
      (__attribute__((address_space(1))) void*)(void*)(g),
      (__attribute__((address_space(3))) void*)(l), 16, 0, 0);
}

#define FENCE asm volatile("" ::: "memory")
#define BAR   __builtin_amdgcn_s_barrier()

// ---------- prep: fp32->bf16 cvt (x) + transposed cvt (w_qkv, w_proj) ----------
__global__ __launch_bounds__(256) void prep(const float* __restrict__ x,
                                            const float* __restrict__ wq,
                                            const float* __restrict__ wp,
                                            unsigned short* __restrict__ xb,
                                            unsigned short* __restrict__ wqT,
                                            unsigned short* __restrict__ wpT) {
  __shared__ unsigned short tile[32][33];
  const int bid = blockIdx.x, tid = threadIdx.x;
  if (bid < 8192) {                     // cvt x
    int i = bid * 256 + tid;
    float4 v = ((const float4*)x)[i];
    ushort4 o;
    o.x = f2b(v.x); o.y = f2b(v.y); o.z = f2b(v.z); o.w = f2b(v.w);
    ((ushort4*)xb)[i] = o;
    return;
  }
  const float* in; unsigned short* out; int R, Cc, tix;
  if (bid < 8192 + 3072) { tix = bid - 8192; in = wq; out = wqT; R = 1024; Cc = 3072; }
  else                   { tix = bid - 8192 - 3072; in = wp; out = wpT; R = 1024; Cc = 1024; }
  const int nbx = Cc / 32;
  const int c0 = (tix % nbx) * 32, r0 = (tix / nbx) * 32;
  const int tx = tid & 31, ty = tid >> 5;
  for (int i = ty; i < 32; i += 8)
    tile[i][tx] = f2b(in[(size_t)(r0 + i) * Cc + c0 + tx]);
  __syncthreads();
  for (int i = ty; i < 32; i += 8)
    out[(size_t)(c0 + i) * R + r0 + tx] = tile[tx][i];
}

// =====================================================================
// Occupancy-first NT bf16 GEMM body, K fixed at 1024.
// RING=3: prefetch depth 2, counted vmcnt (2 bufs in flight).
// RING=2: classic double buffer, vmcnt(0) drain per iter (m97 pattern) —
//         smaller LDS -> more blocks/CU; TLP hides the drain.
// LDS(row,slot16B) = row*64 + slot*16; data chunk = slot ^ ((row>>1)&3);
// source pre-swizzled; read XOR per-lane const: g4 ^ ((frow>>1)&3).
// =====================================================================
template <int BM, int BN, int WM, int WN, int ASTRIDE, int BMODE, int PERB, int RING>
__device__ __forceinline__
void gemm_r3(const unsigned short* __restrict__ A,
             const unsigned short* __restrict__ BT,
             void* __restrict__ Cout,
             const float* __restrict__ bias,
             int N, int NBN) {
  constexpr int THREADS = WM * WN * 64;
  constexpr int MF      = BM / (WM * 16);
  constexpr int NF      = BN / (WN * 16);
  constexpr int TR      = THREADS / 4;        // 64B rows covered per call
  constexpr int ABYTES  = BM * 64;            // A K-tile bytes
  constexpr int TBYTES  = (BM + BN) * 64;     // A+B K-tile bytes
  constexpr int CALLS   = TBYTES / (THREADS * 16);
  constexpr int NT      = 32;                 // K / 32

  extern __shared__ __align__(16) char ldsb[];

  const int tid  = threadIdx.x;
  const int lane = tid & 63, wave = tid >> 6;
  const int wr = wave / WN, wc = wave % WN;
  const int frow = lane & 15, g4 = lane >> 4;
  const int cz = (g4 ^ ((frow >> 1) & 3)) * 16;

  const int cpx = gridDim.x >> 3;
  const int wg  = (blockIdx.x & 7) * cpx + (blockIdx.x >> 3);
  const int bm = wg / NBN, bn = wg % NBN;
  const size_t m0 = (size_t)bm * BM, n0 = (size_t)bn * BN;

  const unsigned short* BTb = PERB ? (BT + (m0 >> 10) * (size_t)(1024 * 1024)) : BT;

  const int trow = tid >> 2;
  const int scol = ((tid & 3) ^ ((tid >> 3) & 3)) * 8;
  const unsigned short* psrc[CALLS];
#pragma unroll
  for (int c = 0; c < CALLS; ++c) {
    const int rr = c * TR + trow;
    psrc[c] = (rr < BM) ? (A + (m0 + rr) * (size_t)ASTRIDE + scol)
                        : (BTb + (size_t)(n0 + rr - BM) * 1024 + scol);
  }

  f32x4 acc[MF][NF];
  if (BMODE == 2) {
    const float* bp = bias + (m0 >> 10) * (size_t)N;
#pragma unroll
    for (int j = 0; j < NF; ++j) {
      float4 bv = *(const float4*)&bp[n0 + wc * (BN / WN) + j * 16 + g4 * 4];
      f32x4 t; t[0] = bv.x; t[1] = bv.y; t[2] = bv.z; t[3] = bv.w;
#pragma unroll
      for (int i = 0; i < MF; ++i) acc[i][j] = t;
    }
  } else {
#pragma unroll
    for (int i = 0; i < MF; ++i)
#pragma unroll
      for (int j = 0; j < NF; ++j) acc[i][j] = f32x4{0.f, 0.f, 0.f, 0.f};
  }

  auto stage = [&](int tk, int buf) {
    char* base = ldsb + buf * TBYTES + wave * 1024;
#pragma unroll
    for (int c = 0; c < CALLS; ++c)
      load_lds16(psrc[c] + tk * 32, base + c * (THREADS * 16));
  };

  const int aoff = (wr * (BM / WM) + frow) * 64 + cz;
  const int boff = ABYTES + (wc * (BN / WN) + frow) * 64 + cz;

  if (RING == 3) { stage(0, 0); stage(1, 1); }
  else           { stage(0, 0); }
  if (RING == 3) asm volatile("s_waitcnt vmcnt(%0)" :: "i"(CALLS) : "memory");
  else           asm volatile("s_waitcnt vmcnt(0)" ::: "memory");
  FENCE; BAR;

  int bcur = 0, bpre = (RING == 3) ? 2 : 1;
#pragma unroll 1
  for (int t = 0; t < NT; ++t) {
    if (RING == 3) { if (t + 2 < NT) stage(t + 2, bpre); }
    else           { if (t + 1 < NT) stage(t + 1, bpre); }
    const char* rb = ldsb + bcur * TBYTES;
    bf16x8 af[MF], bq[NF];
#pragma unroll
    for (int i = 0; i < MF; ++i) af[i] = *(const bf16x8*)(rb + aoff + i * 1024);
#pragma unroll
    for (int j = 0; j < NF; ++j) bq[j] = *(const bf16x8*)(rb + boff + j * 1024);
#pragma unroll
    for (int i = 0; i < MF; ++i)
#pragma unroll
      for (int j = 0; j < NF; ++j)
        acc[i][j] = __builtin_amdgcn_mfma_f32_16x16x32_bf16(bq[j], af[i],
                                                            acc[i][j], 0, 0, 0);
    if (RING == 3 && t + 2 < NT)
      asm volatile("s_waitcnt vmcnt(%0)" :: "i"(CALLS) : "memory");
    else
      asm volatile("s_waitcnt vmcnt(0)" ::: "memory");
    FENCE; BAR;
    if (RING == 3) {
      bcur = (bcur == 2) ? 0 : bcur + 1;
      bpre = (bpre == 2) ? 0 : bpre + 1;
    } else {
      bcur ^= 1; bpre ^= 1;
    }
  }

  const size_t mbase = m0 + wr * (BM / WM) + frow;
  const size_t nbase = n0 + wc * (BN / WN) + g4 * 4;
  if (BMODE == 2) {
    float* C = (float*)Cout;
#pragma unroll
    for (int i = 0; i < MF; ++i)
#pragma unroll
      for (int j = 0; j < NF; ++j) {
        float4 o; o.x = acc[i][j][0]; o.y = acc[i][j][1];
        o.z = acc[i][j][2]; o.w = acc[i][j][3];
        *(float4*)&C[(mbase + i * 16) * N + nbase + j * 16] = o;
      }
  } else {
    unsigned short* C = (unsigned short*)Cout;
#pragma unroll
    for (int i = 0; i < MF; ++i)
#pragma unroll
      for (int j = 0; j < NF; ++j) {
        ushort4 o; o.x = f2b(acc[i][j][0]); o.y = f2b(acc[i][j][1]);
        o.z = f2b(acc[i][j][2]); o.w = f2b(acc[i][j][3]);
        *(ushort4*)&C[(mbase + i * 16) * N + nbase + j * 16] = o;
      }
  }
}

// g_qkv: 128x256 tile, 8 waves (2x4), RING-2 dbuf 48KB -> 3 blocks/CU (24 waves/CU).
__global__ __launch_bounds__(512, 6) void g_qkv(const unsigned short* __restrict__ A,
                                                const unsigned short* __restrict__ BT,
                                                void* __restrict__ C,
                                                const float* __restrict__ bias, int N, int NBN) {
  gemm_r3<128, 256, 2, 4, 1024, 0, 0, 2>(A, BT, C, bias, N, NBN);
}
// g_out: 128x128 tile, 4 waves, ring-3 48KB (grid-limited to 2 blocks/CU anyway).
__global__ __launch_bounds__(256, 3) void g_out(const unsigned short* __restrict__ A,
                                                const unsigned short* __restrict__ BT,
                                                void* __restrict__ C,
                                                const float* __restrict__ bias, int N, int NBN) {
  gemm_r3<128, 128, 2, 2, NQKV, 2, 1, 3>(A, BT, C, bias, N, NBN);
}

// ------------- stats_part: grid 256 (bh x 2 halves). Double-buffered
// n-major staging (counted vmcnt(4)); LDS transpose to d-major (144B
// rows); G/P/mk/mv partials via MFMA (+ones); coalesced dump. -------------
__global__ __launch_bounds__(256) void stats_part(const unsigned short* __restrict__ qkvb,
                                                  float* __restrict__ spart) {
  __shared__ __align__(16) char smem[51200];
  unsigned short (*kd)[72] = (unsigned short(*)[72])(smem);              //  9216B
  unsigned short (*vd)[72] = (unsigned short(*)[72])(smem + 9216);       //  9216B
  char* knb = smem + 18432;                                              // 2x 8192B
  char* vnb = smem + 34816;                                              // 2x 8192B

  const int bh2 = blockIdx.x;
  const int bh = bh2 >> 1, half = bh2 & 1;
  const int b = bh >> 4, h = bh & 15;
  const int tid = threadIdx.x;
  const int lane = tid & 63, wave = tid >> 6;
  const int frow = lane & 15;
  const int fk = (lane >> 4) * 8;

  const unsigned short* kg = qkvb + (size_t)b * 1024 * 3072 + 1024 + h * 64;
  const unsigned short* vg = qkvb + (size_t)b * 1024 * 3072 + 2048 + h * 64;

  typedef __attribute__((ext_vector_type(8))) unsigned short u16x8;
  u16x8 onesu = {0x3F80, 0x3F80, 0x3F80, 0x3F80, 0x3F80, 0x3F80, 0x3F80, 0x3F80};
  const bf16x8 ones = __builtin_bit_cast(bf16x8, onesu);

  f32x4 accG[4], accP[4], accK1, accV1;
#pragma unroll
  for (int j = 0; j < 4; ++j) {
    accG[j] = f32x4{0.f, 0.f, 0.f, 0.f};
    accP[j] = f32x4{0.f, 0.f, 0.f, 0.f};
  }
  accK1 = f32x4{0.f, 0.f, 0.f, 0.f};
  accV1 = f32x4{0.f, 0.f, 0.f, 0.f};

  const size_t srcn = (size_t)(tid >> 3) * 3072 + (tid & 7) * 8;  // hop1 source
  const int td = tid & 63, tng = tid >> 6;                        // hop2 thread map

  auto issue = [&](int ch, int buf) {
    const size_t nb0 = (size_t)half * 512 + (size_t)ch * 64;
#pragma unroll
    for (int c = 0; c < 2; ++c) {
      load_lds16(kg + (nb0 + 32 * c) * 3072 + srcn, knb + buf * 8192 + c * 4096 + wave * 1024);
      load_lds16(vg + (nb0 + 32 * c) * 3072 + srcn, vnb + buf * 8192 + c * 4096 + wave * 1024);
    }
  };

  issue(0, 0);   // prologue
#pragma unroll 1
  for (int ch = 0; ch < 8; ++ch) {
    if (ch + 1 < 8) {
      issue(ch + 1, (ch + 1) & 1);
      asm volatile("s_waitcnt vmcnt(4)" ::: "memory");  // drain chunk ch only
    } else {
      asm volatile("s_waitcnt vmcnt(0)" ::: "memory");
    }
    FENCE; BAR;
    {
      const unsigned short (*kn)[64] = (const unsigned short(*)[64])(knb + (ch & 1) * 8192);
      const unsigned short (*vn)[64] = (const unsigned short(*)[64])(vnb + (ch & 1) * 8192);
      alignas(16) unsigned short pk[16], pv[16];
#pragma unroll
      for (int j = 0; j < 16; ++j) {
        pk[j] = kn[tng * 16 + j][td];
        pv[j] = vn[tng * 16 + j][td];
      }
      *(uint4*)&kd[td][tng * 16]     = *(const uint4*)pk;
      *(uint4*)&kd[td][tng * 16 + 8] = *(const uint4*)(pk + 8);
      *(uint4*)&vd[td][tng * 16]     = *(const uint4*)pv;
      *(uint4*)&vd[td][tng * 16 + 8] = *(const uint4*)(pv + 8);
    }
    FENCE; BAR;
#pragma unroll
    for (int ks = 0; ks < 2; ++ks) {
      const int nb = ks * 32 + fk;
      bf16x8 afk = *(const bf16x8*)&kd[wave * 16 + frow][nb];
      bf16x8 afv = *(const bf16x8*)&vd[wave * 16 + frow][nb];
      bf16x8 kf[4], vf[4];
#pragma unroll
      for (int j = 0; j < 4; ++j) {
        kf[j] = *(const bf16x8*)&kd[j * 16 + frow][nb];
        vf[j] = *(const bf16x8*)&vd[j * 16 + frow][nb];
      }
#pragma unroll
      for (int j = 0; j < 4; ++j) {
        accG[j] = __builtin_amdgcn_mfma_f32_16x16x32_bf16(afk, kf[j], accG[j], 0, 0, 0);
        accP[j] = __builtin_amdgcn_mfma_f32_16x16x32_bf16(afk, vf[j], accP[j], 0, 0, 0);
      }
      accK1 = __builtin_amdgcn_mfma_f32_16x16x32_bf16(afk, ones, accK1, 0, 0, 0);
      accV1 = __builtin_amdgcn_mfma_f32_16x16x32_bf16(afv, ones, accV1, 0, 0, 0);
    }
    FENCE; BAR;   // kd/vd reuse protection
  }

  // coalesced partial dump: word-major [bh2][w][tid]
  float* dst = spart + (size_t)bh2 * 40 * 256;
#pragma unroll
  for (int j = 0; j < 4; ++j)
#pragma unroll
    for (int r = 0; r < 4; ++r) dst[(j * 4 + r) * 256 + tid] = accG[j][r];
#pragma unroll
  for (int j = 0; j < 4; ++j)
#pragma unroll
    for (int r = 0; r < 4; ++r) dst[(16 + j * 4 + r) * 256 + tid] = accP[j][r];
#pragma unroll
  for (int r = 0; r < 4; ++r) dst[(32 + r) * 256 + tid] = accK1[r];
#pragma unroll
  for (int r = 0; r < 4; ++r) dst[(36 + r) * 256 + tid] = accV1[r];
}

// ------------- gd_wc: grid 128. Sum partials, 4 GD iters, then build
// WcT from W kept in LDS (bf16, stride-72). Emits bvec. -------------
__global__ __launch_bounds__(256) void gd_wc(const float* __restrict__ spart,
                                             const unsigned short* __restrict__ wpT,
                                             unsigned short* __restrict__ WcT,
                                             float* __restrict__ bvec) {
  __shared__ __align__(16) char smem[52224];
  float (*Gs)[68] = (float(*)[68])(smem);
  float (*Ps)[68] = (float(*)[68])(smem + 17408);
  float (*Ws)[68] = (float(*)[68])(smem + 34816);
  unsigned short (*wb16)[72] = (unsigned short(*)[72])(smem);  // aliases Gs (dead post-GD)
  __shared__ float mks[64], mvs[64], bs[64];

  const int bh = blockIdx.x, b = bh >> 4, h = bh & 15;
  const int tid = threadIdx.x;
  const int lane = tid & 63, wave = tid >> 6;
  const int frow = lane & 15, g4 = lane >> 4, fk = g4 * 8;

  const float* s0 = spart + (size_t)(bh * 2) * 40 * 256;
  const float* s1 = spart + (size_t)(bh * 2 + 1) * 40 * 256;
  float fsum[40];
#pragma unroll
  for (int w = 0; w < 40; ++w) fsum[w] = s0[w * 256 + tid] + s1[w * 256 + tid];

  const float invN = 1.0f / (float)SEQ;
  const int orow = wave * 16 + (lane >> 4) * 4;
#pragma unroll
  for (int j = 0; j < 4; ++j)
#pragma unroll
    for (int r = 0; r < 4; ++r) {
      Gs[orow + r][j * 16 + frow] = fsum[j * 4 + r] * invN;
      Ps[orow + r][j * 16 + frow] = fsum[16 + j * 4 + r] * invN;
    }
  if (frow == 0) {
#pragma unroll
    for (int r = 0; r < 4; ++r) {
      mks[orow + r] = fsum[32 + r] * invN;
      mvs[orow + r] = fsum[36 + r] * invN;
    }
  }
  const int r = tid >> 2;
  const int c0 = (tid & 3) * 16;
  if (tid < 64) bs[tid] = 0.f;
#pragma unroll
  for (int c = 0; c < 16; ++c) Ws[r][c0 + c] = 0.f;
  __syncthreads();

  for (int it = 0; it < 4; ++it) {
    float wn[16];
#pragma unroll
    for (int c = 0; c < 16; ++c)
      wn[c] = Ws[r][c0 + c] + Ps[r][c0 + c] - mks[r] * bs[c0 + c];
    for (int j = 0; j < 64; ++j) {
      float g = Gs[r][j];
#pragma unroll
      for (int c = 0; c < 16; ++c) wn[c] -= g * Ws[j][c0 + c];
    }
    float bn = 0.f;
    if (tid < 64) {
      bn = mvs[tid];
      for (int j = 0; j < 64; ++j) bn -= mks[j] * Ws[j][tid];
    }
    __syncthreads();
#pragma unroll
    for (int c = 0; c < 16; ++c) Ws[r][c0 + c] = wn[c];
    if (tid < 64) bs[tid] = bn;
    __syncthreads();
  }

  if (tid < 64) bvec[(size_t)bh * HDIM + tid] = bs[tid];

  // W (fp32, Ws) -> bf16 wb16 (aliases Gs; Gs dead after GD loop)
#pragma unroll
  for (int c = 0; c < 16; ++c)
    wb16[r][c0 + c] = f2b(Ws[r][c0 + c]);
  __syncthreads();

  // WcT build: 4 p-blocks of 256 (wave covers 64 p-rows each)
  unsigned short* dstb = WcT + (size_t)b * 1024 * 1024;
#pragma unroll 1
  for (int pblk = 0; pblk < 4; ++pblk) {
    const int p0 = pblk * 256 + wave * 64;
    f32x4 acc[4][4];
#pragma unroll
    for (int i = 0; i < 4; ++i)
#pragma unroll
      for (int j = 0; j < 4; ++j) acc[i][j] = f32x4{0.f, 0.f, 0.f, 0.f};
#pragma unroll
    for (int kk = 0; kk < 2; ++kk) {
      bf16x8 af[4], bq[4];
#pragma unroll
      for (int i = 0; i < 4; ++i)
        af[i] = *(const bf16x8*)&wpT[(size_t)(p0 + i * 16 + frow) * 1024 + h * 64 + kk * 32 + fk];
#pragma unroll
      for (int j = 0; j < 4; ++j)
        bq[j] = *(const bf16x8*)&wb16[j * 16 + frow][kk * 32 + fk];
#pragma unroll
      for (int i = 0; i < 4; ++i)
#pragma unroll
        for (int j = 0; j < 4; ++j)
          acc[i][j] = __builtin_amdgcn_mfma_f32_16x16x32_bf16(bq[j], af[i], acc[i][j], 0, 0, 0);
    }
#pragma unroll
    for (int i = 0; i < 4; ++i)
#pragma unroll
      for (int j = 0; j < 4; ++j) {
        ushort4 o; o.x = f2b(acc[i][j][0]); o.y = f2b(acc[i][j][1]);
        o.z = f2b(acc[i][j][2]); o.w = f2b(acc[i][j][3]);
        *(ushort4*)&dstb[(size_t)(p0 + i * 16 + frow) * 1024 + h * 64 + j * 16 + g4 * 4] = o;
      }
  }
}

// ------------- bc_part: part[cc][b][p] = sum_{c in chunk} bvec[b][c]*wp[c][p] -------------
__global__ __launch_bounds__(256) void bc_part(const float* __restrict__ wp,
                                               const float* __restrict__ bvec,
                                               float* __restrict__ part) {
  const int p  = blockIdx.x * 256 + threadIdx.x;   // 4 blocks in x
  const int cc = blockIdx.y;                       // 16 chunks of 64
  float s[8];
#pragma unroll
  for (int b = 0; b < 8; ++b) s[b] = 0.f;
  const int c0 = cc * 64;
  for (int c = c0; c < c0 + 64; ++c) {
    float w = wp[(size_t)c * 1024 + p];
#pragma unroll
    for (int b = 0; b < 8; ++b) s[b] += bvec[b * 1024 + c] * w;
  }
  float* dst = part + (size_t)cc * 8192;
#pragma unroll
  for (int b = 0; b < 8; ++b) dst[b * 1024 + p] = s[b];
}

// bc[b][p] = b_proj[p] + sum_cc part[cc][b][p]
__global__ __launch_bounds__(256) void bc_reduce(const float* __restrict__ part,
                                                 const float* __restrict__ b_proj,
                                                 float* __restrict__ bc) {
  const int idx = blockIdx.x * 256 + threadIdx.x;
  const int p = idx & 1023;
  float s = b_proj[p];
#pragma unroll
  for (int cc = 0; cc < 16; ++cc) s += part[(size_t)cc * 8192 + idx];
  bc[idx] = s;
}

extern "C" void kernel_launch(void* const* d_in, const int* in_sizes, int n_in,
                              void* d_out, int out_size, void* d_ws, size_t ws_size,
                              hipStream_t stream) {
  const float* x      = (const float*)d_in[0];
  const float* w_qkv  = (const float*)d_in[1];
  const float* w_proj = (const float*)d_in[2];
  const float* b_proj = (const float*)d_in[3];

  // workspace layout (bytes)
  char* ws = (char*)d_ws;
  unsigned short* xb    = (unsigned short*)(ws + 0);          //  16,777,216
  float*          spart = (float*)(ws + 0);                   //  10,485,760 (aliases xb; xb dead after g_qkv)
  unsigned short* wqT   = (unsigned short*)(ws + 16777216);   //   6,291,456
  unsigned short* wpT   = (unsigned short*)(ws + 23068672);   //   2,097,152
  unsigned short* qkvb  = (unsigned short*)(ws + 25165824);   //  50,331,648
  unsigned short* WcT   = (unsigned short*)(ws + 109051904);  //  16,777,216
  float*          bvec  = (float*)(ws + 126877696);           //      32,768
  float*          bc    = (float*)(ws + 126910464);           //      32,768
  float*          bpart = (float*)(ws + 126943232);           //     524,288
  if (ws_size < (size_t)127467520) return;  // clean fail if workspace too small

  hipFuncSetAttribute((const void*)g_qkv, hipFuncAttributeMaxDynamicSharedMemorySize, 49152);
  hipFuncSetAttribute((const void*)g_out, hipFuncAttributeMaxDynamicSharedMemorySize, 49152);

  // prep: cvt x (8192 blocks) + transpose-cvt wq (3072) + wp (1024)
  prep<<<dim3(8192 + 3072 + 1024), 256, 0, stream>>>(x, w_qkv, w_proj, xb, wqT, wpT);
  // qkv = xb @ wqT^T : M=8192, N=3072 -> 64*12 = 768 blocks (128x256, ring-2, 3/CU)
  g_qkv<<<dim3(768), dim3(512), 49152, stream>>>(xb, wqT, qkvb, nullptr, NQKV, 12);
  // per-(b,h)-half G/P/mk/mv partials (all 256 CUs, dbuf staging)
  stats_part<<<256, 256, 0, stream>>>(qkvb, spart);
  // GD solve + WcT build fused (W stays in LDS)
  gd_wc<<<128, 256, 0, stream>>>(spart, wpT, WcT, bvec);
  bc_part<<<dim3(4, 16), 256, 0, stream>>>(w_proj, bvec, bpart);
  bc_reduce<<<32, 256, 0, stream>>>(bpart, b_proj, bc);
  // out = q @ WcT_b^T + bc_b : M=8192, N=1024 -> 64*8 = 512 blocks (128x128, 3/CU)
  g_out<<<dim3(512), dim3(256), 49152, stream>>>(qkvb, WcT, d_out, bc, DIMC, 8);
}

// Round 21
// 163.053 us; speedup vs baseline: 1.5991x; 1.5991x over previous
//
#include <hip/hip_runtime.h>

// MTTT attention, MI355X gfx950.  (r21 = revert to r18 champion config:
// ring-2 experiment spilled registers — launch_bounds(512,6) forced VGPR
// 52->40, 397MB scratch writes, g_qkv 178us. 2 blocks/CU is the max for
// the 128x256 tile; r18 measured best total 163.1us.)
//
// Algebra: inner GD loop needs only G=k^Tk/N, P=k^Tv/N, mk, mv:
//   W <- W + P - G*W - mk (x) b ;  b <- mv - mk*W   (old W,b on RHS)
// Fusion: out = q·Wc_b + bc_b with Wc_{b,h} = W_{b,h} @ wp_h,
//   bc_b = b_proj + sum_c b_b[c]*wp[c,:]

#define SEQ    1024
#define NBATCH 8
#define DIMC   1024
#define NHEAD  16
#define HDIM   64
#define MROWS  8192      // NBATCH*SEQ
#define NQKV   3072

typedef __attribute__((ext_vector_type(8))) __bf16 bf16x8;
typedef __attribute__((ext_vector_type(4))) float  f32x4;

__device__ __forceinline__ unsigned short f2b(float f) {
  union { float f; unsigned int u; } v; v.f = f;
  unsigned int r = (v.u + 0x7FFFu + ((v.u >> 16) & 1u)) >> 16; // RNE
  return (unsigned short)r;
}

// async global->LDS, 16B per lane; LDS dest = wave-uniform base + lane*16
__device__ __forceinline__ void load_lds16(const void* g, void* l) {
  __builtin_amdgcn_global_load_lds(
      (__attribute__((address_space(1))) void*)(void*)(g),
      (__attribute__((address_space(3))) void*)(l), 16, 0, 0);
}

#define FENCE asm volatile("" ::: "memory")
#define BAR   __builtin_amdgcn_s_barrier()

// ---------- prep: fp32->bf16 cvt (x) + transposed cvt (w_qkv, w_proj) ----------
__global__ __launch_bounds__(256) void prep(const float* __restrict__ x,
                                            const float* __restrict__ wq,
                                            const float* __restrict__ wp,
                                            unsigned short* __restrict__ xb,
                                            unsigned short* __restrict__ wqT,
                                            unsigned short* __restrict__ wpT) {
  __shared__ unsigned short tile[32][33];
  const int bid = blockIdx.x, tid = threadIdx.x;
  if (bid < 8192) {                     // cvt x
    int i = bid * 256 + tid;
    float4 v = ((const float4*)x)[i];
    ushort4 o;
    o.x = f2b(v.x); o.y = f2b(v.y); o.z = f2b(v.z); o.w = f2b(v.w);
    ((ushort4*)xb)[i] = o;
    return;
  }
  const float* in; unsigned short* out; int R, Cc, tix;
  if (bid < 8192 + 3072) { tix = bid - 8192; in = wq; out = wqT; R = 1024; Cc = 3072; }
  else                   { tix = bid - 8192 - 3072; in = wp; out = wpT; R = 1024; Cc = 1024; }
  const int nbx = Cc / 32;
  const int c0 = (tix % nbx) * 32, r0 = (tix / nbx) * 32;
  const int tx = tid & 31, ty = tid >> 5;
  for (int i = ty; i < 32; i += 8)
    tile[i][tx] = f2b(in[(size_t)(r0 + i) * Cc + c0 + tx]);
  __syncthreads();
  for (int i = ty; i < 32; i += 8)
    out[(size_t)(c0 + i) * R + r0 + tx] = tile[tx][i];
}

// =====================================================================
// Occupancy-first NT bf16 GEMM body, K fixed at 1024. Ring-3 LDS,
// prefetch depth 2, counted vmcnt, one barrier/iter.
// LDS(row,slot16B) = row*64 + slot*16; data chunk = slot ^ ((row>>1)&3);
// source pre-swizzled; read XOR per-lane const: g4 ^ ((frow>>1)&3).
// =====================================================================
template <int BM, int BN, int WM, int WN, int ASTRIDE, int BMODE, int PERB>
__device__ __forceinline__
void gemm_r3(const unsigned short* __restrict__ A,
             const unsigned short* __restrict__ BT,
             void* __restrict__ Cout,
             const float* __restrict__ bias,
             int N, int NBN) {
  constexpr int THREADS = WM * WN * 64;
  constexpr int MF      = BM / (WM * 16);
  constexpr int NF      = BN / (WN * 16);
  constexpr int TR      = THREADS / 4;        // 64B rows covered per call
  constexpr int ABYTES  = BM * 64;            // A K-tile bytes
  constexpr int TBYTES  = (BM + BN) * 64;     // A+B K-tile bytes
  constexpr int CALLS   = TBYTES / (THREADS * 16);
  constexpr int NT      = 32;                 // K / 32

  extern __shared__ __align__(16) char ldsb[];

  const int tid  = threadIdx.x;
  const int lane = tid & 63, wave = tid >> 6;
  const int wr = wave / WN, wc = wave % WN;
  const int frow = lane & 15, g4 = lane >> 4;
  const int cz = (g4 ^ ((frow >> 1) & 3)) * 16;

  const int cpx = gridDim.x >> 3;
  const int wg  = (blockIdx.x & 7) * cpx + (blockIdx.x >> 3);
  const int bm = wg / NBN, bn = wg % NBN;
  const size_t m0 = (size_t)bm * BM, n0 = (size_t)bn * BN;

  const unsigned short* BTb = PERB ? (BT + (m0 >> 10) * (size_t)(1024 * 1024)) : BT;

  const int trow = tid >> 2;
  const int scol = ((tid & 3) ^ ((tid >> 3) & 3)) * 8;
  const unsigned short* psrc[CALLS];
#pragma unroll
  for (int c = 0; c < CALLS; ++c) {
    const int rr = c * TR + trow;
    psrc[c] = (rr < BM) ? (A + (m0 + rr) * (size_t)ASTRIDE + scol)
                        : (BTb + (size_t)(n0 + rr - BM) * 1024 + scol);
  }

  f32x4 acc[MF][NF];
  if (BMODE == 2) {
    const float* bp = bias + (m0 >> 10) * (size_t)N;
#pragma unroll
    for (int j = 0; j < NF; ++j) {
      float4 bv = *(const float4*)&bp[n0 + wc * (BN / WN) + j * 16 + g4 * 4];
      f32x4 t; t[0] = bv.x; t[1] = bv.y; t[2] = bv.z; t[3] = bv.w;
#pragma unroll
      for (int i = 0; i < MF; ++i) acc[i][j] = t;
    }
  } else {
#pragma unroll
    for (int i = 0; i < MF; ++i)
#pragma unroll
      for (int j = 0; j < NF; ++j) acc[i][j] = f32x4{0.f, 0.f, 0.f, 0.f};
  }

  auto stage = [&](int tk, int buf) {
    char* base = ldsb + buf * TBYTES + wave * 1024;
#pragma unroll
    for (int c = 0; c < CALLS; ++c)
      load_lds16(psrc[c] + tk * 32, base + c * (THREADS * 16));
  };

  const int aoff = (wr * (BM / WM) + frow) * 64 + cz;
  const int boff = ABYTES + (wc * (BN / WN) + frow) * 64 + cz;

  stage(0, 0); stage(1, 1);
  asm volatile("s_waitcnt vmcnt(%0)" :: "i"(CALLS) : "memory");
  FENCE; BAR;

  int bcur = 0, bpre = 2;
#pragma unroll 1
  for (int t = 0; t < NT; ++t) {
    if (t + 2 < NT) stage(t + 2, bpre);
    const char* rb = ldsb + bcur * TBYTES;
    bf16x8 af[MF], bq[NF];
#pragma unroll
    for (int i = 0; i < MF; ++i) af[i] = *(const bf16x8*)(rb + aoff + i * 1024);
#pragma unroll
    for (int j = 0; j < NF; ++j) bq[j] = *(const bf16x8*)(rb + boff + j * 1024);
#pragma unroll
    for (int i = 0; i < MF; ++i)
#pragma unroll
      for (int j = 0; j < NF; ++j)
        acc[i][j] = __builtin_amdgcn_mfma_f32_16x16x32_bf16(bq[j], af[i],
                                                            acc[i][j], 0, 0, 0);
    if (t + 2 < NT) asm volatile("s_waitcnt vmcnt(%0)" :: "i"(CALLS) : "memory");
    else            asm volatile("s_waitcnt vmcnt(0)" ::: "memory");
    FENCE; BAR;
    bcur = (bcur == 2) ? 0 : bcur + 1;
    bpre = (bpre == 2) ? 0 : bpre + 1;
  }

  const size_t mbase = m0 + wr * (BM / WM) + frow;
  const size_t nbase = n0 + wc * (BN / WN) + g4 * 4;
  if (BMODE == 2) {
    float* C = (float*)Cout;
#pragma unroll
    for (int i = 0; i < MF; ++i)
#pragma unroll
      for (int j = 0; j < NF; ++j) {
        float4 o; o.x = acc[i][j][0]; o.y = acc[i][j][1];
        o.z = acc[i][j][2]; o.w = acc[i][j][3];
        *(float4*)&C[(mbase + i * 16) * N + nbase + j * 16] = o;
      }
  } else {
    unsigned short* C = (unsigned short*)Cout;
#pragma unroll
    for (int i = 0; i < MF; ++i)
#pragma unroll
      for (int j = 0; j < NF; ++j) {
        ushort4 o; o.x = f2b(acc[i][j][0]); o.y = f2b(acc[i][j][1]);
        o.z = f2b(acc[i][j][2]); o.w = f2b(acc[i][j][3]);
        *(ushort4*)&C[(mbase + i * 16) * N + nbase + j * 16] = o;
      }
  }
}

// g_qkv: 128x256 tile, 8 waves (2x4), 72KB LDS -> 2 blocks/CU (measured best: 67us).
__global__ __launch_bounds__(512, 4) void g_qkv(const unsigned short* __restrict__ A,
                                                const unsigned short* __restrict__ BT,
                                                void* __restrict__ C,
                                                const float* __restrict__ bias, int N, int NBN) {
  gemm_r3<128, 256, 2, 4, 1024, 0, 0>(A, BT, C, bias, N, NBN);
}
// g_out: 128x128 tile, 4 waves, 48KB -> 3 blocks/CU (measured best for N=1024).
__global__ __launch_bounds__(256, 3) void g_out(const unsigned short* __restrict__ A,
                                                const unsigned short* __restrict__ BT,
                                                void* __restrict__ C,
                                                const float* __restrict__ bias, int N, int NBN) {
  gemm_r3<128, 128, 2, 2, NQKV, 2, 1>(A, BT, C, bias, N, NBN);
}

// ------------- stats_part: grid 256 (bh x 2 halves). Each block stages
// k,v for 512 n-values (8 chunks), accumulates G/P/mk/mv partials via
// MFMA, writes 40 floats/thread word-major (coalesced) to spart. -------------
__global__ __launch_bounds__(256) void stats_part(const unsigned short* __restrict__ qkvb,
                                                  float* __restrict__ spart) {
  __shared__ __align__(16) char smem[51200];
  unsigned short (*kd)[136] = (unsigned short(*)[136])(smem);            // 17408B
  unsigned short (*vd)[136] = (unsigned short(*)[136])(smem + 17408);    // 17408B
  unsigned short (*kn)[64]  = (unsigned short(*)[64])(smem + 34816);     //  8192B
  unsigned short (*vn)[64]  = (unsigned short(*)[64])(smem + 43008);     //  8192B

  const int bh2 = blockIdx.x;
  const int bh = bh2 >> 1, half = bh2 & 1;
  const int b = bh >> 4, h = bh & 15;
  const int tid = threadIdx.x;
  const int lane = tid & 63, wave = tid >> 6;
  const int frow = lane & 15;
  const int fk = (lane >> 4) * 8;

  const unsigned short* kg = qkvb + (size_t)b * 1024 * 3072 + 1024 + h * 64;
  const unsigned short* vg = qkvb + (size_t)b * 1024 * 3072 + 2048 + h * 64;

  typedef __attribute__((ext_vector_type(8))) unsigned short u16x8;
  u16x8 onesu = {0x3F80, 0x3F80, 0x3F80, 0x3F80, 0x3F80, 0x3F80, 0x3F80, 0x3F80};
  const bf16x8 ones = __builtin_bit_cast(bf16x8, onesu);

  f32x4 accG[4], accP[4], accK1, accV1;
#pragma unroll
  for (int j = 0; j < 4; ++j) {
    accG[j] = f32x4{0.f, 0.f, 0.f, 0.f};
    accP[j] = f32x4{0.f, 0.f, 0.f, 0.f};
  }
  accK1 = f32x4{0.f, 0.f, 0.f, 0.f};
  accV1 = f32x4{0.f, 0.f, 0.f, 0.f};

  const size_t srcn = (size_t)(tid >> 3) * 3072 + (tid & 7) * 8;  // hop1 source
  const int td = tid & 63, tng = tid >> 6;                        // hop2 thread map

  for (int ch = 0; ch < 8; ++ch) {
    const size_t nb0 = (size_t)half * 512 + (size_t)ch * 64;
#pragma unroll
    for (int c = 0; c < 2; ++c) {
      load_lds16(kg + (nb0 + 32 * c) * 3072 + srcn, (char*)kn + c * 4096 + wave * 1024);
      load_lds16(vg + (nb0 + 32 * c) * 3072 + srcn, (char*)vn + c * 4096 + wave * 1024);
    }
    asm volatile("s_waitcnt vmcnt(0)" ::: "memory");
    FENCE; BAR;
    {
      alignas(16) unsigned short pk[16], pv[16];
#pragma unroll
      for (int j = 0; j < 16; ++j) {
        pk[j] = kn[tng * 16 + j][td];
        pv[j] = vn[tng * 16 + j][td];
      }
      *(uint4*)&kd[td][tng * 16]     = *(const uint4*)pk;
      *(uint4*)&kd[td][tng * 16 + 8] = *(const uint4*)(pk + 8);
      *(uint4*)&vd[td][tng * 16]     = *(const uint4*)pv;
      *(uint4*)&vd[td][tng * 16 + 8] = *(const uint4*)(pv + 8);
    }
    FENCE; BAR;
#pragma unroll
    for (int ks = 0; ks < 2; ++ks) {
      const int nb = ks * 32 + fk;
      bf16x8 afk = *(const bf16x8*)&kd[wave * 16 + frow][nb];
      bf16x8 afv = *(const bf16x8*)&vd[wave * 16 + frow][nb];
      bf16x8 kf[4], vf[4];
#pragma unroll
      for (int j = 0; j < 4; ++j) {
        kf[j] = *(const bf16x8*)&kd[j * 16 + frow][nb];
        vf[j] = *(const bf16x8*)&vd[j * 16 + frow][nb];
      }
#pragma unroll
      for (int j = 0; j < 4; ++j) {
        accG[j] = __builtin_amdgcn_mfma_f32_16x16x32_bf16(afk, kf[j], accG[j], 0, 0, 0);
        accP[j] = __builtin_amdgcn_mfma_f32_16x16x32_bf16(afk, vf[j], accP[j], 0, 0, 0);
      }
      accK1 = __builtin_amdgcn_mfma_f32_16x16x32_bf16(afk, ones, accK1, 0, 0, 0);
      accV1 = __builtin_amdgcn_mfma_f32_16x16x32_bf16(afv, ones, accV1, 0, 0, 0);
    }
    FENCE; BAR;
  }

  // coalesced partial dump: word-major [bh2][w][tid]
  float* dst = spart + (size_t)bh2 * 40 * 256;
#pragma unroll
  for (int j = 0; j < 4; ++j)
#pragma unroll
    for (int r = 0; r < 4; ++r) dst[(j * 4 + r) * 256 + tid] = accG[j][r];
#pragma unroll
  for (int j = 0; j < 4; ++j)
#pragma unroll
    for (int r = 0; r < 4; ++r) dst[(16 + j * 4 + r) * 256 + tid] = accP[j][r];
#pragma unroll
  for (int r = 0; r < 4; ++r) dst[(32 + r) * 256 + tid] = accK1[r];
#pragma unroll
  for (int r = 0; r < 4; ++r) dst[(36 + r) * 256 + tid] = accV1[r];
}

// ------------- gd_solve: grid 128. Sum the two partials, 4 GD iters,
//               emit W (bf16 forward layout) + b. -------------
__global__ __launch_bounds__(256) void gd_solve(const float* __restrict__ spart,
                                                unsigned short* __restrict__ Wfb,
                                                float* __restrict__ bvec) {
  __shared__ float Gs[64][68];
  __shared__ float Ps[64][68];
  __shared__ float Ws[64][68];
  __shared__ float mks[64], mvs[64], bs[64];

  const int bh = blockIdx.x;
  const int tid = threadIdx.x;
  const int lane = tid & 63, wave = tid >> 6;
  const int frow = lane & 15;

  const float* s0 = spart + (size_t)(bh * 2) * 40 * 256;
  const float* s1 = spart + (size_t)(bh * 2 + 1) * 40 * 256;
  float fsum[40];
#pragma unroll
  for (int w = 0; w < 40; ++w) fsum[w] = s0[w * 256 + tid] + s1[w * 256 + tid];

  const float invN = 1.0f / (float)SEQ;
  const int orow = wave * 16 + (lane >> 4) * 4;
#pragma unroll
  for (int j = 0; j < 4; ++j)
#pragma unroll
    for (int r = 0; r < 4; ++r) {
      Gs[orow + r][j * 16 + frow] = fsum[j * 4 + r] * invN;
      Ps[orow + r][j * 16 + frow] = fsum[16 + j * 4 + r] * invN;
    }
  if (frow == 0) {
#pragma unroll
    for (int r = 0; r < 4; ++r) {
      mks[orow + r] = fsum[32 + r] * invN;
      mvs[orow + r] = fsum[36 + r] * invN;
    }
  }
  const int r = tid >> 2;
  const int c0 = (tid & 3) * 16;
  if (tid < 64) bs[tid] = 0.f;
#pragma unroll
  for (int c = 0; c < 16; ++c) Ws[r][c0 + c] = 0.f;
  __syncthreads();

  for (int it = 0; it < 4; ++it) {
    float wn[16];
#pragma unroll
    for (int c = 0; c < 16; ++c)
      wn[c] = Ws[r][c0 + c] + Ps[r][c0 + c] - mks[r] * bs[c0 + c];
    for (int j = 0; j < 64; ++j) {
      float g = Gs[r][j];
#pragma unroll
      for (int c = 0; c < 16; ++c) wn[c] -= g * Ws[j][c0 + c];
    }
    float bn = 0.f;
    if (tid < 64) {
      bn = mvs[tid];
      for (int j = 0; j < 64; ++j) bn -= mks[j] * Ws[j][tid];
    }
    __syncthreads();
#pragma unroll
    for (int c = 0; c < 16; ++c) Ws[r][c0 + c] = wn[c];
    if (tid < 64) bs[tid] = bn;
    __syncthreads();
  }

  unsigned short* wout = Wfb + (size_t)bh * HDIM * HDIM;
#pragma unroll
  for (int c = 0; c < 16; ++c)
    wout[(size_t)r * HDIM + c0 + c] = f2b(Ws[r][c0 + c]);
  if (tid < 64) bvec[(size_t)bh * HDIM + tid] = bs[tid];
}

// ------------- wc_build (y<4): WcT; (y==4): bc_part -------------
__global__ __launch_bounds__(256) void wc_build(const unsigned short* __restrict__ wpT,
                                                const unsigned short* __restrict__ Wfb,
                                                unsigned short* __restrict__ WcT,
                                                const float* __restrict__ wp,
                                                const float* __restrict__ bvec,
                                                float* __restrict__ part) {
  const int tid = threadIdx.x;
  if (blockIdx.y == 4) {
    if (blockIdx.x >= 64) return;
    const int p  = (blockIdx.x & 3) * 256 + tid;
    const int cc = blockIdx.x >> 2;
    float s[8];
#pragma unroll
    for (int b = 0; b < 8; ++b) s[b] = 0.f;
    const int c0 = cc * 64;
    for (int c = c0; c < c0 + 64; ++c) {
      float w = wp[(size_t)c * 1024 + p];
#pragma unroll
      for (int b = 0; b < 8; ++b) s[b] += bvec[b * 1024 + c] * w;
    }
    float* dst = part + (size_t)cc * 8192;
#pragma unroll
    for (int b = 0; b < 8; ++b) dst[b * 1024 + p] = s[b];
    return;
  }
  const int bh = blockIdx.x;
  const int pblk = blockIdx.y;
  const int b = bh >> 4, h = bh & 15;
  const int lane = tid & 63, wave = tid >> 6;
  const int frow = lane & 15, g4 = lane >> 4, fk = g4 * 8;
  const int p0 = pblk * 256 + wave * 64;

  f32x4 acc[4][4];
#pragma unroll
  for (int i = 0; i < 4; ++i)
#pragma unroll
    for (int j = 0; j < 4; ++j) acc[i][j] = f32x4{0.f, 0.f, 0.f, 0.f};

  const unsigned short* wb = Wfb + (size_t)bh * 4096;
#pragma unroll
  for (int kk = 0; kk < 2; ++kk) {
    bf16x8 af[4], bq[4];
#pragma unroll
    for (int i = 0; i < 4; ++i)
      af[i] = *(const bf16x8*)&wpT[(size_t)(p0 + i * 16 + frow) * 1024 + h * 64 + kk * 32 + fk];
#pragma unroll
    for (int j = 0; j < 4; ++j)
      bq[j] = *(const bf16x8*)&wb[(size_t)(j * 16 + frow) * 64 + kk * 32 + fk];
#pragma unroll
    for (int i = 0; i < 4; ++i)
#pragma unroll
      for (int j = 0; j < 4; ++j)
        acc[i][j] = __builtin_amdgcn_mfma_f32_16x16x32_bf16(bq[j], af[i], acc[i][j], 0, 0, 0);
  }

  unsigned short* dst = WcT + (size_t)b * 1024 * 1024;
#pragma unroll
  for (int i = 0; i < 4; ++i)
#pragma unroll
    for (int j = 0; j < 4; ++j) {
      ushort4 o; o.x = f2b(acc[i][j][0]); o.y = f2b(acc[i][j][1]);
      o.z = f2b(acc[i][j][2]); o.w = f2b(acc[i][j][3]);
      *(ushort4*)&dst[(size_t)(p0 + i * 16 + frow) * 1024 + h * 64 + j * 16 + g4 * 4] = o;
    }
}

// bc[b][p] = b_proj[p] + sum_cc part[cc][b][p]
__global__ __launch_bounds__(256) void bc_reduce(const float* __restrict__ part,
                                                 const float* __restrict__ b_proj,
                                                 float* __restrict__ bc) {
  const int idx = blockIdx.x * 256 + threadIdx.x;
  const int p = idx & 1023;
  float s = b_proj[p];
#pragma unroll
  for (int cc = 0; cc < 16; ++cc) s += part[(size_t)cc * 8192 + idx];
  bc[idx] = s;
}

extern "C" void kernel_launch(void* const* d_in, const int* in_sizes, int n_in,
                              void* d_out, int out_size, void* d_ws, size_t ws_size,
                              hipStream_t stream) {
  const float* x      = (const float*)d_in[0];
  const float* w_qkv  = (const float*)d_in[1];
  const float* w_proj = (const float*)d_in[2];
  const float* b_proj = (const float*)d_in[3];

  // workspace layout (bytes)
  char* ws = (char*)d_ws;
  unsigned short* xb    = (unsigned short*)(ws + 0);          //  16,777,216
  float*          spart = (float*)(ws + 0);                   //  10,485,760 (aliases xb; xb dead after g_qkv)
  unsigned short* wqT   = (unsigned short*)(ws + 16777216);   //   6,291,456
  unsigned short* wpT   = (unsigned short*)(ws + 23068672);   //   2,097,152
  unsigned short* qkvb  = (unsigned short*)(ws + 25165824);   //  50,331,648
  unsigned short* WcT   = (unsigned short*)(ws + 109051904);  //  16,777,216
  unsigned short* Wfb   = (unsigned short*)(ws + 125829120);  //   1,048,576
  float*          bvec  = (float*)(ws + 126877696);           //      32,768
  float*          bc    = (float*)(ws + 126910464);           //      32,768
  float*          bpart = (float*)(ws + 126943232);           //     524,288
  if (ws_size < (size_t)127467520) return;  // clean fail if workspace too small

  hipFuncSetAttribute((const void*)g_qkv, hipFuncAttributeMaxDynamicSharedMemorySize, 73728);
  hipFuncSetAttribute((const void*)g_out, hipFuncAttributeMaxDynamicSharedMemorySize, 49152);

  // prep: cvt x (8192 blocks) + transpose-cvt wq (3072) + wp (1024)
  prep<<<dim3(8192 + 3072 + 1024), 256, 0, stream>>>(x, w_qkv, w_proj, xb, wqT, wpT);
  // qkv = xb @ wqT^T : M=8192, N=3072 -> 64*12 = 768 blocks (128x256, 2/CU)
  g_qkv<<<dim3(768), dim3(512), 73728, stream>>>(xb, wqT, qkvb, nullptr, NQKV, 12);
  // per-(b,h)-half G/P/mk/mv partials (all 256 CUs), then GD solve
  stats_part<<<256, 256, 0, stream>>>(qkvb, spart);
  gd_solve<<<128, 256, 0, stream>>>(spart, Wfb, bvec);
  // wc_build (y<4) + bc_part (y==4)
  wc_build<<<dim3(128, 5), 256, 0, stream>>>(wpT, Wfb, WcT, w_proj, bvec, bpart);
  bc_reduce<<<32, 256, 0, stream>>>(bpart, b_proj, bc);
  // out = q @ WcT_b^T + bc_b : M=8192, N=1024 -> 64*8 = 512 blocks (128x128, 3/CU)
  g_out<<<dim3(512), dim3(256), 49152, stream>>>(qkvb, WcT, d_out, bc, DIMC, 8);
}